// Round 1
// 408.045 us; speedup vs baseline: 1.6111x; 1.6111x over previous
//
#include <hip/hip_runtime.h>
#include <math.h>

#define B_ 2
#define N_ 2048
#define C_ 1024
#define H_ 16
#define D_ 64

typedef __attribute__((ext_vector_type(8))) short short8v;
typedef __attribute__((ext_vector_type(4))) short short4v;
typedef __attribute__((ext_vector_type(4))) float f32x4;

static __device__ __forceinline__ short f2bf(float f) {
    union { float f; unsigned u; } v; v.f = f;
    unsigned r = v.u + 0x7FFFu + ((v.u >> 16) & 1u);   // RNE
    return (short)(r >> 16);
}

// Split fp32 into hi/lo truncated bf16: f = hi + lo + O(2^-16 * f).
// a*b ~= ah*bh + ah*bl + al*bh  (dropped al*bl ~ 2^-16 rel) -> fp32-grade GEMM.
static __device__ __forceinline__ void splitbf(float f, short& h, short& l) {
    union { float f; unsigned u; } v; v.f = f;
    const unsigned uh = v.u & 0xFFFF0000u;
    h = (short)(uh >> 16);
    union { unsigned u; float f; } w; w.u = uh;
    union { float f; unsigned u; } x; x.f = f - w.f;   // exact (Sterbenz)
    l = (short)(x.u >> 16);
}

// ---------------------------------------------------------------------------
// Split-bf16 MFMA GEMM: C = A(MxK) @ B(KxN), row-major fp32 in/out.
// 128x64 tile, BK=32, 4 waves (2x2), each wave 4x2 frags of 16x16x32 bf16.
// Fragment conventions identical to the verified attn_mfma below:
//   A-frag lane(lq,hq) = A[m=lq][k=hq*8+e]; B-frag = Bt[n=lq][k=hq*8+e];
//   acc[r] -> row = hq*4+r, col = lq.
// LDS rows padded to 40 shorts (80 B = 5x16 B): b128-aligned, ~2-way banks.
// ---------------------------------------------------------------------------
#define GKSTR 40

__global__ __launch_bounds__(256) void gemm_x3(const float* __restrict__ A,
                                               const float* __restrict__ Bm,
                                               float* __restrict__ Cm,
                                               int K, int N) {
    __shared__ __align__(16) short Ahi[128][GKSTR];
    __shared__ __align__(16) short Alo[128][GKSTR];
    __shared__ __align__(16) short Bhi[64][GKSTR];
    __shared__ __align__(16) short Blo[64][GKSTR];

    const int t  = threadIdx.x;
    const int w  = t >> 6;
    const int l  = t & 63;
    const int lq = l & 15;
    const int hq = l >> 4;
    const int wr = w >> 1;                 // wave row (m) 0..1
    const int wc = w & 1;                  // wave col (n) 0..1
    const int m0 = blockIdx.y * 128;
    const int n0 = blockIdx.x * 64;

    // A staging: idx = it*256+t -> row = it*32 + (t>>3), kc = (t&7)*4.
    // 8 consecutive lanes read 128 contiguous bytes of one A row (coalesced).
    const int arow = t >> 3;               // 0..31 (+32 per it)
    const int akc  = (t & 7) * 4;          // 0,4,...,28
    // B staging: wave w owns k-slice bkq..bkq+7, lane l owns column n0+l.
    // At fixed kk the wave reads 64 consecutive floats (coalesced).
    const int bn   = t & 63;
    const int bkq  = w * 8;

    f32x4 acc[4][2];
#pragma unroll
    for (int mi = 0; mi < 4; ++mi)
#pragma unroll
        for (int ni = 0; ni < 2; ++ni) acc[mi][ni] = (f32x4){0.f, 0.f, 0.f, 0.f};

    for (int k0 = 0; k0 < K; k0 += 32) {
        // ---- global loads (issued before barrier: overlap prior compute) ----
        float4 af[4];
#pragma unroll
        for (int it = 0; it < 4; ++it)
            af[it] = *(const float4*)&A[(size_t)(m0 + arow + it * 32) * K + k0 + akc];
        float bf[8];
#pragma unroll
        for (int kk = 0; kk < 8; ++kk)
            bf[kk] = Bm[(size_t)(k0 + bkq + kk) * N + n0 + bn];

        // ---- in-register hi/lo split (VALU overlaps prior MFMA) ----
        short4v ah[4], al[4];
#pragma unroll
        for (int it = 0; it < 4; ++it) {
            short h, lo2;
            splitbf(af[it].x, h, lo2); ah[it][0] = h; al[it][0] = lo2;
            splitbf(af[it].y, h, lo2); ah[it][1] = h; al[it][1] = lo2;
            splitbf(af[it].z, h, lo2); ah[it][2] = h; al[it][2] = lo2;
            splitbf(af[it].w, h, lo2); ah[it][3] = h; al[it][3] = lo2;
        }
        short8v bh, bl;
#pragma unroll
        for (int kk = 0; kk < 8; ++kk) {
            short h, lo2;
            splitbf(bf[kk], h, lo2); bh[kk] = h; bl[kk] = lo2;
        }

        __syncthreads();
#pragma unroll
        for (int it = 0; it < 4; ++it) {
            *(short4v*)&Ahi[arow + it * 32][akc] = ah[it];
            *(short4v*)&Alo[arow + it * 32][akc] = al[it];
        }
        *(short8v*)&Bhi[bn][bkq] = bh;
        *(short8v*)&Blo[bn][bkq] = bl;
        __syncthreads();

        // ---- fragments + 24 MFMA (8 chains of 3) ----
        short8v amh[4], aml[4], bnh[2], bnl[2];
#pragma unroll
        for (int mi = 0; mi < 4; ++mi) {
            amh[mi] = *(const short8v*)&Ahi[wr * 64 + mi * 16 + lq][hq * 8];
            aml[mi] = *(const short8v*)&Alo[wr * 64 + mi * 16 + lq][hq * 8];
        }
#pragma unroll
        for (int ni = 0; ni < 2; ++ni) {
            bnh[ni] = *(const short8v*)&Bhi[wc * 32 + ni * 16 + lq][hq * 8];
            bnl[ni] = *(const short8v*)&Blo[wc * 32 + ni * 16 + lq][hq * 8];
        }
#pragma unroll
        for (int mi = 0; mi < 4; ++mi)
#pragma unroll
            for (int ni = 0; ni < 2; ++ni) {
                acc[mi][ni] = __builtin_amdgcn_mfma_f32_16x16x32_bf16(amh[mi], bnh[ni], acc[mi][ni], 0, 0, 0);
                acc[mi][ni] = __builtin_amdgcn_mfma_f32_16x16x32_bf16(amh[mi], bnl[ni], acc[mi][ni], 0, 0, 0);
                acc[mi][ni] = __builtin_amdgcn_mfma_f32_16x16x32_bf16(aml[mi], bnh[ni], acc[mi][ni], 0, 0, 0);
            }
    }

    // ---- epilogue: row = hq*4+r, col = lq (16-lane 64B segments) ----
#pragma unroll
    for (int mi = 0; mi < 4; ++mi)
#pragma unroll
        for (int ni = 0; ni < 2; ++ni) {
            const int col = n0 + wc * 32 + ni * 16 + lq;
#pragma unroll
            for (int r = 0; r < 4; ++r) {
                const int row = m0 + wr * 64 + mi * 16 + hq * 4 + r;
                Cm[(size_t)row * N + col] = acc[mi][ni][r];
            }
        }
}

// ---------------------------------------------------------------------------
// Two-pass MFMA attention (unchanged, harness-verified).
// ---------------------------------------------------------------------------
#define KSTR 72
#define VSTR 136
#define PSTR 136

__global__ __launch_bounds__(256) void attn_mfma(const float* __restrict__ q,
                                                 const float* __restrict__ kv,
                                                 const int* __restrict__ mask,
                                                 float* __restrict__ out_att,
                                                 float* __restrict__ out_w) {
    __shared__ __align__(16) short Ks[128][KSTR];        // 18432 B
    __shared__ __align__(16) short Vt[64][VSTR];         // 17408 B
    __shared__ __align__(16) short Ps[4][16][PSTR];      // 17408 B
    __shared__ float linv_s[4][16];
    __shared__ int   mcol_s[128];

    const int t  = threadIdx.x;
    const int w  = t >> 6;
    const int l  = t & 63;
    const int lq = l & 15;
    const int hq = l >> 4;

    const int qb = blockIdx.x;          // 0..31
    const int h  = blockIdx.y;          // 0..15
    const int b  = blockIdx.z;          // 0..1
    const int i0 = qb * 64 + w * 16;    // wave's first q row

    // ---- Q fragments: A[m=lq][k=kb*32+hq*8+e] ----
    short8v qa[2];
    {
        const float* qrow = q + ((size_t)(b * N_ + i0 + lq)) * C_ + h * D_;
#pragma unroll
        for (int kb = 0; kb < 2; ++kb) {
            const float4 f0 = *(const float4*)&qrow[kb * 32 + hq * 8];
            const float4 f1 = *(const float4*)&qrow[kb * 32 + hq * 8 + 4];
            short8v s;
            s[0] = f2bf(f0.x); s[1] = f2bf(f0.y); s[2] = f2bf(f0.z); s[3] = f2bf(f0.w);
            s[4] = f2bf(f1.x); s[5] = f2bf(f1.y); s[6] = f2bf(f1.z); s[7] = f2bf(f1.w);
            qa[kb] = s;
        }
    }

    int mr[4];
#pragma unroll
    for (int r = 0; r < 4; ++r) mr[r] = mask[b * N_ + i0 + hq * 4 + r];

    const float* kbase = kv + (size_t)b * N_ * 2 * C_ + h * D_;
    const float* vbase = kbase + C_;

    // ---------------- pass 1: row sums only ----------------
    float lsum[4] = {0.f, 0.f, 0.f, 0.f};
    for (int tile = 0; tile < 16; ++tile) {
        const int jt = tile * 128;
        __syncthreads();
#pragma unroll
        for (int it = 0; it < 4; ++it) {
            const int idx = it * 256 + t;
            const int j = idx >> 3, d0 = (idx & 7) * 8;
            const float* src = kbase + (size_t)(jt + j) * (2 * C_) + d0;
            const float4 f0 = *(const float4*)&src[0];
            const float4 f1 = *(const float4*)&src[4];
            short8v s;
            s[0] = f2bf(f0.x); s[1] = f2bf(f0.y); s[2] = f2bf(f0.z); s[3] = f2bf(f0.w);
            s[4] = f2bf(f1.x); s[5] = f2bf(f1.y); s[6] = f2bf(f1.z); s[7] = f2bf(f1.w);
            *(short8v*)&Ks[j][d0] = s;
        }
        if (t < 128) mcol_s[t] = mask[b * N_ + jt + t];
        __syncthreads();
#pragma unroll
        for (int cb = 0; cb < 8; ++cb) {
            f32x4 acc = {0.f, 0.f, 0.f, 0.f};
            const short8v b0 = *(short8v*)&Ks[cb * 16 + lq][hq * 8];
            const short8v b1 = *(short8v*)&Ks[cb * 16 + lq][32 + hq * 8];
            acc = __builtin_amdgcn_mfma_f32_16x16x32_bf16(qa[0], b0, acc, 0, 0, 0);
            acc = __builtin_amdgcn_mfma_f32_16x16x32_bf16(qa[1], b1, acc, 0, 0, 0);
            const int mc = mcol_s[cb * 16 + lq];
#pragma unroll
            for (int r = 0; r < 4; ++r)
                lsum[r] += mr[r] ? 1.0f : (mc ? 0.0f : __expf(acc[r] * 0.125f));
        }
    }
    float inv[4];
#pragma unroll
    for (int r = 0; r < 4; ++r) {
        float s = lsum[r];
#pragma unroll
        for (int off = 1; off < 16; off <<= 1) s += __shfl_xor(s, off, 64);
        inv[r] = 1.0f / s;
    }
    if (lq == 0)
#pragma unroll
        for (int r = 0; r < 4; ++r) linv_s[w][hq * 4 + r] = inv[r];

    float* wrow[4];
#pragma unroll
    for (int r = 0; r < 4; ++r)
        wrow[r] = out_w + ((size_t)((b * H_ + h) * N_ + i0 + hq * 4 + r)) * N_;

    f32x4 oacc[4];
#pragma unroll
    for (int db = 0; db < 4; ++db) oacc[db] = (f32x4){0.f, 0.f, 0.f, 0.f};

    // ---------------- pass 2 ----------------
    for (int tile = 0; tile < 16; ++tile) {
        const int jt = tile * 128;
        __syncthreads();
        // K restage (identical code -> identical ev)
#pragma unroll
        for (int it = 0; it < 4; ++it) {
            const int idx = it * 256 + t;
            const int j = idx >> 3, d0 = (idx & 7) * 8;
            const float* src = kbase + (size_t)(jt + j) * (2 * C_) + d0;
            const float4 f0 = *(const float4*)&src[0];
            const float4 f1 = *(const float4*)&src[4];
            short8v s;
            s[0] = f2bf(f0.x); s[1] = f2bf(f0.y); s[2] = f2bf(f0.z); s[3] = f2bf(f0.w);
            s[4] = f2bf(f1.x); s[5] = f2bf(f1.y); s[6] = f2bf(f1.z); s[7] = f2bf(f1.w);
            *(short8v*)&Ks[j][d0] = s;
        }
        // V stage: lane owns rows dp,dp+1; coalesced float2 reads
#pragma unroll
        for (int half = 0; half < 2; ++half) {
            const int j0 = w * 32 + half * 16 + (l >> 5) * 8;
            const int dp = (l & 31) * 2;
            short8v s0, s1;
#pragma unroll
            for (int jj = 0; jj < 8; ++jj) {
                const float2 f = *(const float2*)&vbase[(size_t)(jt + j0 + jj) * (2 * C_) + dp];
                s0[jj] = f2bf(f.x);
                s1[jj] = f2bf(f.y);
            }
            *(short8v*)&Vt[dp + 0][j0] = s0;
            *(short8v*)&Vt[dp + 1][j0] = s1;
        }
        if (t < 128) mcol_s[t] = mask[b * N_ + jt + t];
        __syncthreads();

#pragma unroll
        for (int cb = 0; cb < 8; ++cb) {
            f32x4 acc = {0.f, 0.f, 0.f, 0.f};
            const short8v b0 = *(short8v*)&Ks[cb * 16 + lq][hq * 8];
            const short8v b1 = *(short8v*)&Ks[cb * 16 + lq][32 + hq * 8];
            acc = __builtin_amdgcn_mfma_f32_16x16x32_bf16(qa[0], b0, acc, 0, 0, 0);
            acc = __builtin_amdgcn_mfma_f32_16x16x32_bf16(qa[1], b1, acc, 0, 0, 0);
            const int mc   = mcol_s[cb * 16 + lq];
            const int jcol = cb * 16 + lq;
#pragma unroll
            for (int r = 0; r < 4; ++r) {
                const float ev = mr[r] ? 1.0f : (mc ? 0.0f : __expf(acc[r] * 0.125f));
                wrow[r][jt + jcol] = ev * inv[r];       // normalized weight
                Ps[w][hq * 4 + r][jcol] = f2bf(ev);
            }
        }
        __syncthreads();   // REQUIRED: Ps writes -> cross-lane PV reads

        // att^T += V^T @ P
#pragma unroll
        for (int db = 0; db < 4; ++db)
#pragma unroll
            for (int kb = 0; kb < 4; ++kb) {
                const short8v va = *(short8v*)&Vt[db * 16 + lq][kb * 32 + hq * 8];
                const short8v pb = *(short8v*)&Ps[w][lq][kb * 32 + hq * 8];
                oacc[db] = __builtin_amdgcn_mfma_f32_16x16x32_bf16(va, pb, oacc[db], 0, 0, 0);
            }
    }

    // ---- att: scale accumulators, scalar stores (row=lq, d=db*16+hq*4+r) ----
    {
        const float invi = linv_s[w][lq];
        const size_t abase = ((size_t)(b * N_ + i0 + lq)) * C_ + h * D_;
#pragma unroll
        for (int db = 0; db < 4; ++db)
#pragma unroll
            for (int r = 0; r < 4; ++r)
                out_att[abase + db * 16 + hq * 4 + r] = oacc[db][r] * invi;
    }
}

// ---------------------------------------------------------------------------
extern "C" void kernel_launch(void* const* d_in, const int* in_sizes, int n_in,
                              void* d_out, int out_size, void* d_ws, size_t ws_size,
                              hipStream_t stream) {
    const float* hs   = (const float*)d_in[0];
    const float* ehs  = (const float*)d_in[1];
    const int*   mask = (const int*)d_in[2];
    const float* W_q  = (const float*)d_in[3];
    const float* W_c  = (const float*)d_in[4];

    float* out_att = (float*)d_out;
    float* out_w   = (float*)d_out + (size_t)B_ * N_ * C_;

    float* ws_q  = (float*)d_ws;
    float* ws_kv = ws_q + (size_t)B_ * N_ * C_;

    gemm_x3<<<dim3(C_ / 64, (B_ * N_) / 128), 256, 0, stream>>>(
        hs, W_q, ws_q, C_, C_);
    gemm_x3<<<dim3((2 * C_) / 64, (B_ * N_) / 128), 256, 0, stream>>>(
        ehs, W_c, ws_kv, C_, 2 * C_);

    attn_mfma<<<dim3(N_ / 64, H_, B_), 256, 0, stream>>>(
        ws_q, ws_kv, mask, out_att, out_w);
}

// Round 2
// 365.462 us; speedup vs baseline: 1.7988x; 1.1165x over previous
//
#include <hip/hip_runtime.h>
#include <math.h>

#define B_ 2
#define N_ 2048
#define C_ 1024
#define H_ 16
#define D_ 64

typedef __attribute__((ext_vector_type(8))) short short8v;
typedef __attribute__((ext_vector_type(4))) short short4v;
typedef __attribute__((ext_vector_type(4))) float f32x4;

static __device__ __forceinline__ short f2bf(float f) {
    union { float f; unsigned u; } v; v.f = f;
    unsigned r = v.u + 0x7FFFu + ((v.u >> 16) & 1u);   // RNE
    return (short)(r >> 16);
}

// Split fp32 into hi/lo truncated bf16: f = hi + lo + O(2^-16 * f).
// a*b ~= ah*bh + ah*bl + al*bh  (dropped al*bl ~ 2^-16 rel) -> fp32-grade GEMM.
static __device__ __forceinline__ void splitbf(float f, short& h, short& l) {
    union { float f; unsigned u; } v; v.f = f;
    const unsigned uh = v.u & 0xFFFF0000u;
    h = (short)(uh >> 16);
    union { unsigned u; float f; } w; w.u = uh;
    union { float f; unsigned u; } x; x.f = f - w.f;   // exact (Sterbenz)
    l = (short)(x.u >> 16);
}

// ---------------------------------------------------------------------------
// Split-bf16 MFMA GEMM: C = A(MxK) @ B(KxN), row-major fp32 in, bf16 out.
// (bf16 out: every consumer immediately RNE-rounds to bf16 anyway; rounding
//  the identical fp32 accumulator here gives bitwise-identical attn inputs.)
// 128x64 tile, BK=32, 4 waves (2x2), each wave 4x2 frags of 16x16x32 bf16.
//   A-frag lane(lq,hq) = A[m=lq][k=hq*8+e]; B-frag = Bt[n=lq][k=hq*8+e];
//   acc[r] -> row = hq*4+r, col = lq.
// ---------------------------------------------------------------------------
#define GKSTR 40

__global__ __launch_bounds__(256) void gemm_x3(const float* __restrict__ A,
                                               const float* __restrict__ Bm,
                                               short* __restrict__ Cm,
                                               int K, int N) {
    __shared__ __align__(16) short Ahi[128][GKSTR];
    __shared__ __align__(16) short Alo[128][GKSTR];
    __shared__ __align__(16) short Bhi[64][GKSTR];
    __shared__ __align__(16) short Blo[64][GKSTR];

    const int t  = threadIdx.x;
    const int w  = t >> 6;
    const int l  = t & 63;
    const int lq = l & 15;
    const int hq = l >> 4;
    const int wr = w >> 1;                 // wave row (m) 0..1
    const int wc = w & 1;                  // wave col (n) 0..1
    const int m0 = blockIdx.y * 128;
    const int n0 = blockIdx.x * 64;

    const int arow = t >> 3;               // 0..31 (+32 per it)
    const int akc  = (t & 7) * 4;          // 0,4,...,28
    const int bn   = t & 63;
    const int bkq  = w * 8;

    f32x4 acc[4][2];
#pragma unroll
    for (int mi = 0; mi < 4; ++mi)
#pragma unroll
        for (int ni = 0; ni < 2; ++ni) acc[mi][ni] = (f32x4){0.f, 0.f, 0.f, 0.f};

    for (int k0 = 0; k0 < K; k0 += 32) {
        // ---- global loads (issued before barrier: overlap prior compute) ----
        float4 af[4];
#pragma unroll
        for (int it = 0; it < 4; ++it)
            af[it] = *(const float4*)&A[(size_t)(m0 + arow + it * 32) * K + k0 + akc];
        float bf[8];
#pragma unroll
        for (int kk = 0; kk < 8; ++kk)
            bf[kk] = Bm[(size_t)(k0 + bkq + kk) * N + n0 + bn];

        // ---- in-register hi/lo split (VALU overlaps prior MFMA) ----
        short4v ah[4], al[4];
#pragma unroll
        for (int it = 0; it < 4; ++it) {
            short h, lo2;
            splitbf(af[it].x, h, lo2); ah[it][0] = h; al[it][0] = lo2;
            splitbf(af[it].y, h, lo2); ah[it][1] = h; al[it][1] = lo2;
            splitbf(af[it].z, h, lo2); ah[it][2] = h; al[it][2] = lo2;
            splitbf(af[it].w, h, lo2); ah[it][3] = h; al[it][3] = lo2;
        }
        short8v bh, bl;
#pragma unroll
        for (int kk = 0; kk < 8; ++kk) {
            short h, lo2;
            splitbf(bf[kk], h, lo2); bh[kk] = h; bl[kk] = lo2;
        }

        __syncthreads();
#pragma unroll
        for (int it = 0; it < 4; ++it) {
            *(short4v*)&Ahi[arow + it * 32][akc] = ah[it];
            *(short4v*)&Alo[arow + it * 32][akc] = al[it];
        }
        *(short8v*)&Bhi[bn][bkq] = bh;
        *(short8v*)&Blo[bn][bkq] = bl;
        __syncthreads();

        // ---- fragments + 24 MFMA (8 chains of 3) ----
        short8v amh[4], aml[4], bnh[2], bnl[2];
#pragma unroll
        for (int mi = 0; mi < 4; ++mi) {
            amh[mi] = *(const short8v*)&Ahi[wr * 64 + mi * 16 + lq][hq * 8];
            aml[mi] = *(const short8v*)&Alo[wr * 64 + mi * 16 + lq][hq * 8];
        }
#pragma unroll
        for (int ni = 0; ni < 2; ++ni) {
            bnh[ni] = *(const short8v*)&Bhi[wc * 32 + ni * 16 + lq][hq * 8];
            bnl[ni] = *(const short8v*)&Blo[wc * 32 + ni * 16 + lq][hq * 8];
        }
#pragma unroll
        for (int mi = 0; mi < 4; ++mi)
#pragma unroll
            for (int ni = 0; ni < 2; ++ni) {
                acc[mi][ni] = __builtin_amdgcn_mfma_f32_16x16x32_bf16(amh[mi], bnh[ni], acc[mi][ni], 0, 0, 0);
                acc[mi][ni] = __builtin_amdgcn_mfma_f32_16x16x32_bf16(amh[mi], bnl[ni], acc[mi][ni], 0, 0, 0);
                acc[mi][ni] = __builtin_amdgcn_mfma_f32_16x16x32_bf16(aml[mi], bnh[ni], acc[mi][ni], 0, 0, 0);
            }
    }

    // ---- epilogue: row = hq*4+r, col = lq; bf16 scalar stores ----
#pragma unroll
    for (int mi = 0; mi < 4; ++mi)
#pragma unroll
        for (int ni = 0; ni < 2; ++ni) {
            const int col = n0 + wc * 32 + ni * 16 + lq;
#pragma unroll
            for (int r = 0; r < 4; ++r) {
                const int row = m0 + wr * 64 + mi * 16 + hq * 4 + r;
                Cm[(size_t)row * N + col] = f2bf(acc[mi][ni][r]);
            }
        }
}

// ---------------------------------------------------------------------------
// Transpose bf16 V (columns C..2C of kv_bf) into Vt_g[b][h][d][j].
// Read coalesced rows via LDS tile, write coalesced d-rows. ~8.4 MB each way.
// ---------------------------------------------------------------------------
__global__ __launch_bounds__(256) void v_transpose(const short* __restrict__ kv_bf,
                                                   short* __restrict__ vt) {
    __shared__ __align__(16) short Ls[128][72];
    const int t  = threadIdx.x;
    const int jt = blockIdx.x * 128;
    const int h  = blockIdx.y;
    const int b  = blockIdx.z;
    const short* src = kv_bf + (size_t)b * N_ * 2 * C_ + C_ + h * D_;
#pragma unroll
    for (int it = 0; it < 4; ++it) {
        const int idx = it * 256 + t;
        const int j = idx >> 3, d0 = (idx & 7) * 8;
        *(short8v*)&Ls[j][d0] = *(const short8v*)&src[(size_t)(jt + j) * (2 * C_) + d0];
    }
    __syncthreads();
    short* dst = vt + ((size_t)(b * H_ + h)) * D_ * N_;
#pragma unroll
    for (int it = 0; it < 4; ++it) {
        const int idx = it * 256 + t;
        const int d  = idx >> 4;           // 0..63
        const int j0 = (idx & 15) * 8;
        short8v s;
#pragma unroll
        for (int jj = 0; jj < 8; ++jj) s[jj] = Ls[j0 + jj][d];
        *(short8v*)&dst[(size_t)d * N_ + jt + j0] = s;
    }
}

// ---------------------------------------------------------------------------
// Two-pass MFMA attention, bf16 inputs (pre-converted/pre-transposed).
// Staging is now pure short8v copies: no f2bf, no transpose in-kernel.
// ev of both passes is bitwise-identical (same qa regs, same staged bits).
// ---------------------------------------------------------------------------
#define KSTR 72
#define VSTR 136
#define PSTR 136

__global__ __launch_bounds__(256) void attn_mfma(const short* __restrict__ q,
                                                 const short* __restrict__ kv,
                                                 const short* __restrict__ vtg,
                                                 const int* __restrict__ mask,
                                                 float* __restrict__ out_att,
                                                 float* __restrict__ out_w) {
    __shared__ __align__(16) short Ks[128][KSTR];        // 18432 B
    __shared__ __align__(16) short Vt[64][VSTR];         // 17408 B
    __shared__ __align__(16) short Ps[4][16][PSTR];      // 17408 B
    __shared__ float linv_s[4][16];
    __shared__ int   mcol_s[128];

    const int t  = threadIdx.x;
    const int w  = t >> 6;
    const int l  = t & 63;
    const int lq = l & 15;
    const int hq = l >> 4;

    const int qb = blockIdx.x;          // 0..31
    const int h  = blockIdx.y;          // 0..15
    const int b  = blockIdx.z;          // 0..1
    const int i0 = qb * 64 + w * 16;    // wave's first q row

    // ---- Q fragments: A[m=lq][k=kb*32+hq*8+e], direct bf16 loads ----
    short8v qa[2];
    {
        const short* qrow = q + ((size_t)(b * N_ + i0 + lq)) * C_ + h * D_;
        qa[0] = *(const short8v*)&qrow[hq * 8];
        qa[1] = *(const short8v*)&qrow[32 + hq * 8];
    }

    int mr[4];
#pragma unroll
    for (int r = 0; r < 4; ++r) mr[r] = mask[b * N_ + i0 + hq * 4 + r];

    const short* kbase = kv + (size_t)b * N_ * 2 * C_ + h * D_;
    const short* vtb   = vtg + ((size_t)(b * H_ + h)) * D_ * N_;

    // ---------------- pass 1: row sums only ----------------
    float lsum[4] = {0.f, 0.f, 0.f, 0.f};
    for (int tile = 0; tile < 16; ++tile) {
        const int jt = tile * 128;
        __syncthreads();
#pragma unroll
        for (int it = 0; it < 4; ++it) {
            const int idx = it * 256 + t;
            const int j = idx >> 3, d0 = (idx & 7) * 8;
            *(short8v*)&Ks[j][d0] = *(const short8v*)&kbase[(size_t)(jt + j) * (2 * C_) + d0];
        }
        if (t < 128) mcol_s[t] = mask[b * N_ + jt + t];
        __syncthreads();
#pragma unroll
        for (int cb = 0; cb < 8; ++cb) {
            f32x4 acc = {0.f, 0.f, 0.f, 0.f};
            const short8v b0 = *(short8v*)&Ks[cb * 16 + lq][hq * 8];
            const short8v b1 = *(short8v*)&Ks[cb * 16 + lq][32 + hq * 8];
            acc = __builtin_amdgcn_mfma_f32_16x16x32_bf16(qa[0], b0, acc, 0, 0, 0);
            acc = __builtin_amdgcn_mfma_f32_16x16x32_bf16(qa[1], b1, acc, 0, 0, 0);
            const int mc = mcol_s[cb * 16 + lq];
#pragma unroll
            for (int r = 0; r < 4; ++r)
                lsum[r] += mr[r] ? 1.0f : (mc ? 0.0f : __expf(acc[r] * 0.125f));
        }
    }
    float inv[4];
#pragma unroll
    for (int r = 0; r < 4; ++r) {
        float s = lsum[r];
#pragma unroll
        for (int off = 1; off < 16; off <<= 1) s += __shfl_xor(s, off, 64);
        inv[r] = 1.0f / s;
    }
    if (lq == 0)
#pragma unroll
        for (int r = 0; r < 4; ++r) linv_s[w][hq * 4 + r] = inv[r];

    float* wrow[4];
#pragma unroll
    for (int r = 0; r < 4; ++r)
        wrow[r] = out_w + ((size_t)((b * H_ + h) * N_ + i0 + hq * 4 + r)) * N_;

    f32x4 oacc[4];
#pragma unroll
    for (int db = 0; db < 4; ++db) oacc[db] = (f32x4){0.f, 0.f, 0.f, 0.f};

    // ---------------- pass 2 ----------------
    for (int tile = 0; tile < 16; ++tile) {
        const int jt = tile * 128;
        __syncthreads();
        // K restage (identical bits -> identical ev)
#pragma unroll
        for (int it = 0; it < 4; ++it) {
            const int idx = it * 256 + t;
            const int j = idx >> 3, d0 = (idx & 7) * 8;
            *(short8v*)&Ks[j][d0] = *(const short8v*)&kbase[(size_t)(jt + j) * (2 * C_) + d0];
        }
        // V stage: pre-transposed rows, pure copies (d-row chunks of 128 j)
#pragma unroll
        for (int it = 0; it < 4; ++it) {
            const int idx = it * 256 + t;
            const int d  = idx >> 4;           // 0..63
            const int j0 = (idx & 15) * 8;
            *(short8v*)&Vt[d][j0] = *(const short8v*)&vtb[(size_t)d * N_ + jt + j0];
        }
        if (t < 128) mcol_s[t] = mask[b * N_ + jt + t];
        __syncthreads();

#pragma unroll
        for (int cb = 0; cb < 8; ++cb) {
            f32x4 acc = {0.f, 0.f, 0.f, 0.f};
            const short8v b0 = *(short8v*)&Ks[cb * 16 + lq][hq * 8];
            const short8v b1 = *(short8v*)&Ks[cb * 16 + lq][32 + hq * 8];
            acc = __builtin_amdgcn_mfma_f32_16x16x32_bf16(qa[0], b0, acc, 0, 0, 0);
            acc = __builtin_amdgcn_mfma_f32_16x16x32_bf16(qa[1], b1, acc, 0, 0, 0);
            const int mc   = mcol_s[cb * 16 + lq];
            const int jcol = cb * 16 + lq;
#pragma unroll
            for (int r = 0; r < 4; ++r) {
                const float ev = mr[r] ? 1.0f : (mc ? 0.0f : __expf(acc[r] * 0.125f));
                wrow[r][jt + jcol] = ev * inv[r];       // normalized weight
                Ps[w][hq * 4 + r][jcol] = f2bf(ev);
            }
        }
        __syncthreads();   // REQUIRED: Ps writes -> cross-lane PV reads

        // att^T += V^T @ P
#pragma unroll
        for (int db = 0; db < 4; ++db)
#pragma unroll
            for (int kb = 0; kb < 4; ++kb) {
                const short8v va = *(short8v*)&Vt[db * 16 + lq][kb * 32 + hq * 8];
                const short8v pb = *(short8v*)&Ps[w][lq][kb * 32 + hq * 8];
                oacc[db] = __builtin_amdgcn_mfma_f32_16x16x32_bf16(va, pb, oacc[db], 0, 0, 0);
            }
    }

    // ---- att: scale accumulators, scalar stores (row=lq, d=db*16+hq*4+r) ----
    {
        const float invi = linv_s[w][lq];
        const size_t abase = ((size_t)(b * N_ + i0 + lq)) * C_ + h * D_;
#pragma unroll
        for (int db = 0; db < 4; ++db)
#pragma unroll
            for (int r = 0; r < 4; ++r)
                out_att[abase + db * 16 + hq * 4 + r] = oacc[db][r] * invi;
    }
}

// ---------------------------------------------------------------------------
extern "C" void kernel_launch(void* const* d_in, const int* in_sizes, int n_in,
                              void* d_out, int out_size, void* d_ws, size_t ws_size,
                              hipStream_t stream) {
    const float* hs   = (const float*)d_in[0];
    const float* ehs  = (const float*)d_in[1];
    const int*   mask = (const int*)d_in[2];
    const float* W_q  = (const float*)d_in[3];
    const float* W_c  = (const float*)d_in[4];

    float* out_att = (float*)d_out;
    float* out_w   = (float*)d_out + (size_t)B_ * N_ * C_;

    short* qbf  = (short*)d_ws;                          // B*N*C
    short* kvbf = qbf + (size_t)B_ * N_ * C_;            // B*N*2C
    short* vt   = kvbf + (size_t)B_ * N_ * 2 * C_;       // B*H*D*N

    gemm_x3<<<dim3(C_ / 64, (B_ * N_) / 128), 256, 0, stream>>>(
        hs, W_q, qbf, C_, C_);
    gemm_x3<<<dim3((2 * C_) / 64, (B_ * N_) / 128), 256, 0, stream>>>(
        ehs, W_c, kvbf, C_, 2 * C_);
    v_transpose<<<dim3(N_ / 128, H_, B_), 256, 0, stream>>>(kvbf, vt);

    attn_mfma<<<dim3(N_ / 64, H_, B_), 256, 0, stream>>>(
        qbf, kvbf, vt, mask, out_att, out_w);
}

// Round 3
// 323.518 us; speedup vs baseline: 2.0321x; 1.1297x over previous
//
#include <hip/hip_runtime.h>
#include <math.h>

#define B_ 2
#define N_ 2048
#define C_ 1024
#define H_ 16
#define D_ 64

typedef __attribute__((ext_vector_type(8))) short short8v;
typedef __attribute__((ext_vector_type(4))) short short4v;
typedef __attribute__((ext_vector_type(4))) float f32x4;

static __device__ __forceinline__ short f2bf(float f) {
    union { float f; unsigned u; } v; v.f = f;
    unsigned r = v.u + 0x7FFFu + ((v.u >> 16) & 1u);   // RNE
    return (short)(r >> 16);
}

// Split fp32 into hi/lo truncated bf16: f = hi + lo + O(2^-16 * f).
// a*b ~= ah*bh + ah*bl + al*bh  (dropped al*bl ~ 2^-16 rel) -> fp32-grade GEMM.
static __device__ __forceinline__ void splitbf(float f, short& h, short& l) {
    union { float f; unsigned u; } v; v.f = f;
    const unsigned uh = v.u & 0xFFFF0000u;
    h = (short)(uh >> 16);
    union { unsigned u; float f; } w; w.u = uh;
    union { float f; unsigned u; } x; x.f = f - w.f;   // exact (Sterbenz)
    l = (short)(x.u >> 16);
}

// ---------------------------------------------------------------------------
// Split-bf16 MFMA GEMM, software-pipelined: C = A(MxK)@B(KxN), fp32 in, bf16 out.
// 128x64 tile, BK=32, 4 waves (2x2). Pipeline: preload+presplit k0; per iter
// {barrier; LDS-write; barrier; issue loads(k0+32); ds-read+MFMA; split(k0+32)}
// so global-load latency spans the whole iteration body.
// ---------------------------------------------------------------------------
#define GKSTR 40

__global__ __launch_bounds__(256) void gemm_x3(const float* __restrict__ A,
                                               const float* __restrict__ Bm,
                                               short* __restrict__ Cm,
                                               int K, int N) {
    __shared__ __align__(16) short Ahi[128][GKSTR];
    __shared__ __align__(16) short Alo[128][GKSTR];
    __shared__ __align__(16) short Bhi[64][GKSTR];
    __shared__ __align__(16) short Blo[64][GKSTR];

    const int t  = threadIdx.x;
    const int w  = t >> 6;
    const int l  = t & 63;
    const int lq = l & 15;
    const int hq = l >> 4;
    const int wr = w >> 1;                 // wave row (m) 0..1
    const int wc = w & 1;                  // wave col (n) 0..1
    const int m0 = blockIdx.y * 128;
    const int n0 = blockIdx.x * 64;

    const int arow = t >> 3;               // 0..31 (+32 per it)
    const int akc  = (t & 7) * 4;          // 0,4,...,28
    const int bn   = t & 63;
    const int bkq  = w * 8;

    f32x4 acc[4][2];
#pragma unroll
    for (int mi = 0; mi < 4; ++mi)
#pragma unroll
        for (int ni = 0; ni < 2; ++ni) acc[mi][ni] = (f32x4){0.f, 0.f, 0.f, 0.f};

    // ---- prologue: load + split k0 = 0 ----
    float4 af[4];
    float  bf[8];
#pragma unroll
    for (int it = 0; it < 4; ++it)
        af[it] = *(const float4*)&A[(size_t)(m0 + arow + it * 32) * K + akc];
#pragma unroll
    for (int kk = 0; kk < 8; ++kk)
        bf[kk] = Bm[(size_t)(bkq + kk) * N + n0 + bn];

    short4v ah[4], al[4];
    short8v bh, bl;
#pragma unroll
    for (int it = 0; it < 4; ++it) {
        short h, lo2;
        splitbf(af[it].x, h, lo2); ah[it][0] = h; al[it][0] = lo2;
        splitbf(af[it].y, h, lo2); ah[it][1] = h; al[it][1] = lo2;
        splitbf(af[it].z, h, lo2); ah[it][2] = h; al[it][2] = lo2;
        splitbf(af[it].w, h, lo2); ah[it][3] = h; al[it][3] = lo2;
    }
#pragma unroll
    for (int kk = 0; kk < 8; ++kk) {
        short h, lo2;
        splitbf(bf[kk], h, lo2); bh[kk] = h; bl[kk] = lo2;
    }

    for (int k0 = 0; k0 < K; k0 += 32) {
        __syncthreads();
#pragma unroll
        for (int it = 0; it < 4; ++it) {
            *(short4v*)&Ahi[arow + it * 32][akc] = ah[it];
            *(short4v*)&Alo[arow + it * 32][akc] = al[it];
        }
        *(short8v*)&Bhi[bn][bkq] = bh;
        *(short8v*)&Blo[bn][bkq] = bl;
        __syncthreads();

        const int kn = k0 + 32;
        if (kn < K) {
#pragma unroll
            for (int it = 0; it < 4; ++it)
                af[it] = *(const float4*)&A[(size_t)(m0 + arow + it * 32) * K + kn + akc];
#pragma unroll
            for (int kk = 0; kk < 8; ++kk)
                bf[kk] = Bm[(size_t)(kn + bkq + kk) * N + n0 + bn];
        }

        // ---- fragments + 24 MFMA (8 chains of 3) ----
        short8v amh[4], aml[4], bnh[2], bnl[2];
#pragma unroll
        for (int mi = 0; mi < 4; ++mi) {
            amh[mi] = *(const short8v*)&Ahi[wr * 64 + mi * 16 + lq][hq * 8];
            aml[mi] = *(const short8v*)&Alo[wr * 64 + mi * 16 + lq][hq * 8];
        }
#pragma unroll
        for (int ni = 0; ni < 2; ++ni) {
            bnh[ni] = *(const short8v*)&Bhi[wc * 32 + ni * 16 + lq][hq * 8];
            bnl[ni] = *(const short8v*)&Blo[wc * 32 + ni * 16 + lq][hq * 8];
        }
#pragma unroll
        for (int mi = 0; mi < 4; ++mi)
#pragma unroll
            for (int ni = 0; ni < 2; ++ni) {
                acc[mi][ni] = __builtin_amdgcn_mfma_f32_16x16x32_bf16(amh[mi], bnh[ni], acc[mi][ni], 0, 0, 0);
                acc[mi][ni] = __builtin_amdgcn_mfma_f32_16x16x32_bf16(amh[mi], bnl[ni], acc[mi][ni], 0, 0, 0);
                acc[mi][ni] = __builtin_amdgcn_mfma_f32_16x16x32_bf16(aml[mi], bnh[ni], acc[mi][ni], 0, 0, 0);
            }

        if (kn < K) {
#pragma unroll
            for (int it = 0; it < 4; ++it) {
                short h, lo2;
                splitbf(af[it].x, h, lo2); ah[it][0] = h; al[it][0] = lo2;
                splitbf(af[it].y, h, lo2); ah[it][1] = h; al[it][1] = lo2;
                splitbf(af[it].z, h, lo2); ah[it][2] = h; al[it][2] = lo2;
                splitbf(af[it].w, h, lo2); ah[it][3] = h; al[it][3] = lo2;
            }
#pragma unroll
            for (int kk = 0; kk < 8; ++kk) {
                short h, lo2;
                splitbf(bf[kk], h, lo2); bh[kk] = h; bl[kk] = lo2;
            }
        }
    }

    // ---- epilogue: row = hq*4+r, col = lq; bf16 scalar stores ----
#pragma unroll
    for (int mi = 0; mi < 4; ++mi)
#pragma unroll
        for (int ni = 0; ni < 2; ++ni) {
            const int col = n0 + wc * 32 + ni * 16 + lq;
#pragma unroll
            for (int r = 0; r < 4; ++r) {
                const int row = m0 + wr * 64 + mi * 16 + hq * 4 + r;
                Cm[(size_t)row * N + col] = f2bf(acc[mi][ni][r]);
            }
        }
}

// ---------------------------------------------------------------------------
// Transpose bf16 V (columns C..2C of kv_bf) into Vt_g[b][h][d][j].
// ---------------------------------------------------------------------------
__global__ __launch_bounds__(256) void v_transpose(const short* __restrict__ kv_bf,
                                                   short* __restrict__ vt) {
    __shared__ __align__(16) short Ls[128][72];
    const int t  = threadIdx.x;
    const int jt = blockIdx.x * 128;
    const int h  = blockIdx.y;
    const int b  = blockIdx.z;
    const short* src = kv_bf + (size_t)b * N_ * 2 * C_ + C_ + h * D_;
#pragma unroll
    for (int it = 0; it < 4; ++it) {
        const int idx = it * 256 + t;
        const int j = idx >> 3, d0 = (idx & 7) * 8;
        *(short8v*)&Ls[j][d0] = *(const short8v*)&src[(size_t)(jt + j) * (2 * C_) + d0];
    }
    __syncthreads();
    short* dst = vt + ((size_t)(b * H_ + h)) * D_ * N_;
#pragma unroll
    for (int it = 0; it < 4; ++it) {
        const int idx = it * 256 + t;
        const int d  = idx >> 4;           // 0..63
        const int j0 = (idx & 15) * 8;
        short8v s;
#pragma unroll
        for (int jj = 0; jj < 8; ++jj) s[jj] = Ls[j0 + jj][d];
        *(short8v*)&dst[(size_t)d * N_ + jt + j0] = s;
    }
}

// ---------------------------------------------------------------------------
// Two-pass MFMA attention, bf16 inputs, register-prefetched staging (T14):
// per tile {barrier; LDS-write from regs; barrier; issue next-tile loads;
// compute} so HBM latency hides under MFMA/exp work. XCD-swizzled 1D grid:
// each XCD owns 4 whole (b,h) K/V panels -> panels stay in one L2.
// ev of both passes is bitwise-identical (same qa regs, same staged bits).
// ---------------------------------------------------------------------------
#define KSTR 72
#define VSTR 136
#define PSTR 136

__global__ __launch_bounds__(256) void attn_mfma(const short* __restrict__ q,
                                                 const short* __restrict__ kv,
                                                 const short* __restrict__ vtg,
                                                 const int* __restrict__ mask,
                                                 float* __restrict__ out_att,
                                                 float* __restrict__ out_w) {
    __shared__ __align__(16) short Ks[128][KSTR];        // 18432 B
    __shared__ __align__(16) short Vt[64][VSTR];         // 17408 B
    __shared__ __align__(16) short Ps[4][16][PSTR];      // 17408 B
    __shared__ float linv_s[4][16];
    __shared__ int   mcol_s[128];

    const int t  = threadIdx.x;
    const int w  = t >> 6;
    const int l  = t & 63;
    const int lq = l & 15;
    const int hq = l >> 4;

    // XCD-aware bijective swizzle (1024 blocks, 8 XCDs, 128 each)
    const int lin = blockIdx.x;
    const int swz = (lin & 7) * 128 + (lin >> 3);
    const int qb = swz & 31;            // 0..31
    const int h  = (swz >> 5) & 15;     // 0..15
    const int b  = swz >> 9;            // 0..1
    const int i0 = qb * 64 + w * 16;    // wave's first q row

    // staging decompositions (it-invariant parts)
    const int sj = t >> 3;              // K stage: row = it*32 + sj
    const int sd = (t & 7) * 8;         //          col = sd
    const int vd = t >> 4;              // V stage: row = it*16 + vd
    const int vj = (t & 15) * 8;        //          col = vj

    // ---- Q fragments: A[m=lq][k=kb*32+hq*8+e], direct bf16 loads ----
    short8v qa[2];
    {
        const short* qrow = q + ((size_t)(b * N_ + i0 + lq)) * C_ + h * D_;
        qa[0] = *(const short8v*)&qrow[hq * 8];
        qa[1] = *(const short8v*)&qrow[32 + hq * 8];
    }

    int mr[4];
#pragma unroll
    for (int r = 0; r < 4; ++r) mr[r] = mask[b * N_ + i0 + hq * 4 + r];

    const short* kbase = kv + (size_t)b * N_ * 2 * C_ + h * D_;
    const short* vtb   = vtg + ((size_t)(b * H_ + h)) * D_ * N_;

    // ---------------- pass 1: row sums only ----------------
    float lsum[4] = {0.f, 0.f, 0.f, 0.f};
    short8v kr[4];
    int mpre = 0;
#pragma unroll
    for (int it = 0; it < 4; ++it)
        kr[it] = *(const short8v*)&kbase[(size_t)(it * 32 + sj) * (2 * C_) + sd];
    if (t < 128) mpre = mask[b * N_ + t];

    for (int tile = 0; tile < 16; ++tile) {
        __syncthreads();
#pragma unroll
        for (int it = 0; it < 4; ++it)
            *(short8v*)&Ks[it * 32 + sj][sd] = kr[it];
        if (t < 128) mcol_s[t] = mpre;
        __syncthreads();

        if (tile < 15) {
            const int jn = (tile + 1) * 128;
#pragma unroll
            for (int it = 0; it < 4; ++it)
                kr[it] = *(const short8v*)&kbase[(size_t)(jn + it * 32 + sj) * (2 * C_) + sd];
            if (t < 128) mpre = mask[b * N_ + jn + t];
        }

#pragma unroll
        for (int cb = 0; cb < 8; ++cb) {
            f32x4 acc = {0.f, 0.f, 0.f, 0.f};
            const short8v b0 = *(short8v*)&Ks[cb * 16 + lq][hq * 8];
            const short8v b1 = *(short8v*)&Ks[cb * 16 + lq][32 + hq * 8];
            acc = __builtin_amdgcn_mfma_f32_16x16x32_bf16(qa[0], b0, acc, 0, 0, 0);
            acc = __builtin_amdgcn_mfma_f32_16x16x32_bf16(qa[1], b1, acc, 0, 0, 0);
            const int mc = mcol_s[cb * 16 + lq];
#pragma unroll
            for (int r = 0; r < 4; ++r)
                lsum[r] += mr[r] ? 1.0f : (mc ? 0.0f : __expf(acc[r] * 0.125f));
        }
    }
    float inv[4];
#pragma unroll
    for (int r = 0; r < 4; ++r) {
        float s = lsum[r];
#pragma unroll
        for (int off = 1; off < 16; off <<= 1) s += __shfl_xor(s, off, 64);
        inv[r] = 1.0f / s;
    }
    if (lq == 0)
#pragma unroll
        for (int r = 0; r < 4; ++r) linv_s[w][hq * 4 + r] = inv[r];

    float* wrow[4];
#pragma unroll
    for (int r = 0; r < 4; ++r)
        wrow[r] = out_w + ((size_t)((b * H_ + h) * N_ + i0 + hq * 4 + r)) * N_;

    f32x4 oacc[4];
#pragma unroll
    for (int db = 0; db < 4; ++db) oacc[db] = (f32x4){0.f, 0.f, 0.f, 0.f};

    // ---------------- pass 2 ----------------
    short8v vr[4];
#pragma unroll
    for (int it = 0; it < 4; ++it) {
        kr[it] = *(const short8v*)&kbase[(size_t)(it * 32 + sj) * (2 * C_) + sd];
        vr[it] = *(const short8v*)&vtb[(size_t)(it * 16 + vd) * N_ + vj];
    }
    if (t < 128) mpre = mask[b * N_ + t];

    for (int tile = 0; tile < 16; ++tile) {
        const int jt = tile * 128;
        __syncthreads();
#pragma unroll
        for (int it = 0; it < 4; ++it) {
            *(short8v*)&Ks[it * 32 + sj][sd] = kr[it];
            *(short8v*)&Vt[it * 16 + vd][vj] = vr[it];
        }
        if (t < 128) mcol_s[t] = mpre;
        __syncthreads();

        if (tile < 15) {
            const int jn = jt + 128;
#pragma unroll
            for (int it = 0; it < 4; ++it) {
                kr[it] = *(const short8v*)&kbase[(size_t)(jn + it * 32 + sj) * (2 * C_) + sd];
                vr[it] = *(const short8v*)&vtb[(size_t)(it * 16 + vd) * N_ + jn + vj];
            }
            if (t < 128) mpre = mask[b * N_ + jn + t];
        }

#pragma unroll
        for (int cb = 0; cb < 8; ++cb) {
            f32x4 acc = {0.f, 0.f, 0.f, 0.f};
            const short8v b0 = *(short8v*)&Ks[cb * 16 + lq][hq * 8];
            const short8v b1 = *(short8v*)&Ks[cb * 16 + lq][32 + hq * 8];
            acc = __builtin_amdgcn_mfma_f32_16x16x32_bf16(qa[0], b0, acc, 0, 0, 0);
            acc = __builtin_amdgcn_mfma_f32_16x16x32_bf16(qa[1], b1, acc, 0, 0, 0);
            const int mc   = mcol_s[cb * 16 + lq];
            const int jcol = cb * 16 + lq;
#pragma unroll
            for (int r = 0; r < 4; ++r) {
                const float ev = mr[r] ? 1.0f : (mc ? 0.0f : __expf(acc[r] * 0.125f));
                wrow[r][jt + jcol] = ev * inv[r];       // normalized weight
                Ps[w][hq * 4 + r][jcol] = f2bf(ev);
            }
        }
        __syncthreads();   // REQUIRED: Ps writes -> cross-lane PV reads

        // att^T += V^T @ P
#pragma unroll
        for (int db = 0; db < 4; ++db)
#pragma unroll
            for (int kb = 0; kb < 4; ++kb) {
                const short8v va = *(short8v*)&Vt[db * 16 + lq][kb * 32 + hq * 8];
                const short8v pb = *(short8v*)&Ps[w][lq][kb * 32 + hq * 8];
                oacc[db] = __builtin_amdgcn_mfma_f32_16x16x32_bf16(va, pb, oacc[db], 0, 0, 0);
            }
    }

    // ---- att: scale accumulators, scalar stores (row=lq, d=db*16+hq*4+r) ----
    {
        const float invi = linv_s[w][lq];
        const size_t abase = ((size_t)(b * N_ + i0 + lq)) * C_ + h * D_;
#pragma unroll
        for (int db = 0; db < 4; ++db)
#pragma unroll
            for (int r = 0; r < 4; ++r)
                out_att[abase + db * 16 + hq * 4 + r] = oacc[db][r] * invi;
    }
}

// ---------------------------------------------------------------------------
extern "C" void kernel_launch(void* const* d_in, const int* in_sizes, int n_in,
                              void* d_out, int out_size, void* d_ws, size_t ws_size,
                              hipStream_t stream) {
    const float* hs   = (const float*)d_in[0];
    const float* ehs  = (const float*)d_in[1];
    const int*   mask = (const int*)d_in[2];
    const float* W_q  = (const float*)d_in[3];
    const float* W_c  = (const float*)d_in[4];

    float* out_att = (float*)d_out;
    float* out_w   = (float*)d_out + (size_t)B_ * N_ * C_;

    short* qbf  = (short*)d_ws;                          // B*N*C
    short* kvbf = qbf + (size_t)B_ * N_ * C_;            // B*N*2C
    short* vt   = kvbf + (size_t)B_ * N_ * 2 * C_;       // B*H*D*N

    gemm_x3<<<dim3(C_ / 64, (B_ * N_) / 128), 256, 0, stream>>>(
        hs, W_q, qbf, C_, C_);
    gemm_x3<<<dim3((2 * C_) / 64, (B_ * N_) / 128), 256, 0, stream>>>(
        ehs, W_c, kvbf, C_, 2 * C_);
    v_transpose<<<dim3(N_ / 128, H_, B_), 256, 0, stream>>>(kvbf, vt);

    attn_mfma<<<dim3(1024), 256, 0, stream>>>(
        qbf, kvbf, vt, mask, out_att, out_w);
}

// Round 4
// 321.489 us; speedup vs baseline: 2.0449x; 1.0063x over previous
//
#include <hip/hip_runtime.h>
#include <math.h>

#define B_ 2
#define N_ 2048
#define C_ 1024
#define H_ 16
#define D_ 64

typedef __attribute__((ext_vector_type(8))) short short8v;
typedef __attribute__((ext_vector_type(4))) short short4v;
typedef __attribute__((ext_vector_type(4))) float f32x4;

static __device__ __forceinline__ short f2bf(float f) {
    union { float f; unsigned u; } v; v.f = f;
    unsigned r = v.u + 0x7FFFu + ((v.u >> 16) & 1u);   // RNE
    return (short)(r >> 16);
}

// Split fp32 into hi/lo truncated bf16: f = hi + lo + O(2^-16 * f).
// a*b ~= ah*bh + ah*bl + al*bh  (dropped al*bl ~ 2^-16 rel) -> fp32-grade GEMM.
static __device__ __forceinline__ void splitbf(float f, short& h, short& l) {
    union { float f; unsigned u; } v; v.f = f;
    const unsigned uh = v.u & 0xFFFF0000u;
    h = (short)(uh >> 16);
    union { unsigned u; float f; } w; w.u = uh;
    union { float f; unsigned u; } x; x.f = f - w.f;   // exact (Sterbenz)
    l = (short)(x.u >> 16);
}

// ---------------------------------------------------------------------------
// Split-bf16 MFMA GEMM, software-pipelined: C = A(MxK)@B(KxN), fp32 in, bf16 out.
// 128x64 tile, BK=32, 4 waves (2x2). Pipeline: preload+presplit k0; per iter
// {barrier; LDS-write; barrier; issue loads(k0+32); ds-read+MFMA; split(k0+32)}
// so global-load latency spans the whole iteration body.
// ---------------------------------------------------------------------------
#define GKSTR 40

__global__ __launch_bounds__(256) void gemm_x3(const float* __restrict__ A,
                                               const float* __restrict__ Bm,
                                               short* __restrict__ Cm,
                                               int K, int N) {
    __shared__ __align__(16) short Ahi[128][GKSTR];
    __shared__ __align__(16) short Alo[128][GKSTR];
    __shared__ __align__(16) short Bhi[64][GKSTR];
    __shared__ __align__(16) short Blo[64][GKSTR];

    const int t  = threadIdx.x;
    const int w  = t >> 6;
    const int l  = t & 63;
    const int lq = l & 15;
    const int hq = l >> 4;
    const int wr = w >> 1;                 // wave row (m) 0..1
    const int wc = w & 1;                  // wave col (n) 0..1
    const int m0 = blockIdx.y * 128;
    const int n0 = blockIdx.x * 64;

    const int arow = t >> 3;               // 0..31 (+32 per it)
    const int akc  = (t & 7) * 4;          // 0,4,...,28
    const int bn   = t & 63;
    const int bkq  = w * 8;

    f32x4 acc[4][2];
#pragma unroll
    for (int mi = 0; mi < 4; ++mi)
#pragma unroll
        for (int ni = 0; ni < 2; ++ni) acc[mi][ni] = (f32x4){0.f, 0.f, 0.f, 0.f};

    // ---- prologue: load + split k0 = 0 ----
    float4 af[4];
    float  bf[8];
#pragma unroll
    for (int it = 0; it < 4; ++it)
        af[it] = *(const float4*)&A[(size_t)(m0 + arow + it * 32) * K + akc];
#pragma unroll
    for (int kk = 0; kk < 8; ++kk)
        bf[kk] = Bm[(size_t)(bkq + kk) * N + n0 + bn];

    short4v ah[4], al[4];
    short8v bh, bl;
#pragma unroll
    for (int it = 0; it < 4; ++it) {
        short h, lo2;
        splitbf(af[it].x, h, lo2); ah[it][0] = h; al[it][0] = lo2;
        splitbf(af[it].y, h, lo2); ah[it][1] = h; al[it][1] = lo2;
        splitbf(af[it].z, h, lo2); ah[it][2] = h; al[it][2] = lo2;
        splitbf(af[it].w, h, lo2); ah[it][3] = h; al[it][3] = lo2;
    }
#pragma unroll
    for (int kk = 0; kk < 8; ++kk) {
        short h, lo2;
        splitbf(bf[kk], h, lo2); bh[kk] = h; bl[kk] = lo2;
    }

    for (int k0 = 0; k0 < K; k0 += 32) {
        __syncthreads();
#pragma unroll
        for (int it = 0; it < 4; ++it) {
            *(short4v*)&Ahi[arow + it * 32][akc] = ah[it];
            *(short4v*)&Alo[arow + it * 32][akc] = al[it];
        }
        *(short8v*)&Bhi[bn][bkq] = bh;
        *(short8v*)&Blo[bn][bkq] = bl;
        __syncthreads();

        const int kn = k0 + 32;
        if (kn < K) {
#pragma unroll
            for (int it = 0; it < 4; ++it)
                af[it] = *(const float4*)&A[(size_t)(m0 + arow + it * 32) * K + kn + akc];
#pragma unroll
            for (int kk = 0; kk < 8; ++kk)
                bf[kk] = Bm[(size_t)(kn + bkq + kk) * N + n0 + bn];
        }

        // ---- fragments + 24 MFMA (8 chains of 3) ----
        short8v amh[4], aml[4], bnh[2], bnl[2];
#pragma unroll
        for (int mi = 0; mi < 4; ++mi) {
            amh[mi] = *(const short8v*)&Ahi[wr * 64 + mi * 16 + lq][hq * 8];
            aml[mi] = *(const short8v*)&Alo[wr * 64 + mi * 16 + lq][hq * 8];
        }
#pragma unroll
        for (int ni = 0; ni < 2; ++ni) {
            bnh[ni] = *(const short8v*)&Bhi[wc * 32 + ni * 16 + lq][hq * 8];
            bnl[ni] = *(const short8v*)&Blo[wc * 32 + ni * 16 + lq][hq * 8];
        }
#pragma unroll
        for (int mi = 0; mi < 4; ++mi)
#pragma unroll
            for (int ni = 0; ni < 2; ++ni) {
                acc[mi][ni] = __builtin_amdgcn_mfma_f32_16x16x32_bf16(amh[mi], bnh[ni], acc[mi][ni], 0, 0, 0);
                acc[mi][ni] = __builtin_amdgcn_mfma_f32_16x16x32_bf16(amh[mi], bnl[ni], acc[mi][ni], 0, 0, 0);
                acc[mi][ni] = __builtin_amdgcn_mfma_f32_16x16x32_bf16(aml[mi], bnh[ni], acc[mi][ni], 0, 0, 0);
            }

        if (kn < K) {
#pragma unroll
            for (int it = 0; it < 4; ++it) {
                short h, lo2;
                splitbf(af[it].x, h, lo2); ah[it][0] = h; al[it][0] = lo2;
                splitbf(af[it].y, h, lo2); ah[it][1] = h; al[it][1] = lo2;
                splitbf(af[it].z, h, lo2); ah[it][2] = h; al[it][2] = lo2;
                splitbf(af[it].w, h, lo2); ah[it][3] = h; al[it][3] = lo2;
            }
#pragma unroll
            for (int kk = 0; kk < 8; ++kk) {
                short h, lo2;
                splitbf(bf[kk], h, lo2); bh[kk] = h; bl[kk] = lo2;
            }
        }
    }

    // ---- epilogue: row = hq*4+r, col = lq; bf16 scalar stores ----
#pragma unroll
    for (int mi = 0; mi < 4; ++mi)
#pragma unroll
        for (int ni = 0; ni < 2; ++ni) {
            const int col = n0 + wc * 32 + ni * 16 + lq;
#pragma unroll
            for (int r = 0; r < 4; ++r) {
                const int row = m0 + wr * 64 + mi * 16 + hq * 4 + r;
                Cm[(size_t)row * N + col] = f2bf(acc[mi][ni][r]);
            }
        }
}

// ---------------------------------------------------------------------------
// Transpose bf16 V (columns C..2C of kv_bf) into Vt_g[b][h][d][j].
// ---------------------------------------------------------------------------
__global__ __launch_bounds__(256) void v_transpose(const short* __restrict__ kv_bf,
                                                   short* __restrict__ vt) {
    __shared__ __align__(16) short Ls[128][72];
    const int t  = threadIdx.x;
    const int jt = blockIdx.x * 128;
    const int h  = blockIdx.y;
    const int b  = blockIdx.z;
    const short* src = kv_bf + (size_t)b * N_ * 2 * C_ + C_ + h * D_;
#pragma unroll
    for (int it = 0; it < 4; ++it) {
        const int idx = it * 256 + t;
        const int j = idx >> 3, d0 = (idx & 7) * 8;
        *(short8v*)&Ls[j][d0] = *(const short8v*)&src[(size_t)(jt + j) * (2 * C_) + d0];
    }
    __syncthreads();
    short* dst = vt + ((size_t)(b * H_ + h)) * D_ * N_;
#pragma unroll
    for (int it = 0; it < 4; ++it) {
        const int idx = it * 256 + t;
        const int d  = idx >> 4;           // 0..63
        const int j0 = (idx & 15) * 8;
        short8v s;
#pragma unroll
        for (int jj = 0; jj < 8; ++jj) s[jj] = Ls[j0 + jj][d];
        *(short8v*)&dst[(size_t)d * N_ + jt + j0] = s;
    }
}

// ---------------------------------------------------------------------------
// Two-pass MFMA attention, 32 q-rows per wave (block = 128 rows of one (b,h)).
// The wave-shared LDS reads (Ks tile for QK, Vt tile for PV) now feed 2x the
// output rows -> per-output LDS-read volume ~halves; 512 blocks = exactly one
// residency round (2 blocks/CU x 256 CU). Register-prefetched staging (T14),
// XCD-swizzled 1D grid (each XCD owns 4 whole (b,h) panels).
// Per-row math order identical to the 16-row version -> bit-identical output.
// ---------------------------------------------------------------------------
#define KSTR 72
#define VSTR 136
#define PSTR 136

__global__ __launch_bounds__(256) void attn_mfma(const short* __restrict__ q,
                                                 const short* __restrict__ kv,
                                                 const short* __restrict__ vtg,
                                                 const int* __restrict__ mask,
                                                 float* __restrict__ out_att,
                                                 float* __restrict__ out_w) {
    __shared__ __align__(16) short Ks[128][KSTR];        // 18432 B
    __shared__ __align__(16) short Vt[64][VSTR];         // 17408 B
    __shared__ __align__(16) short Ps[4][32][PSTR];      // 34816 B
    __shared__ float linv_s[4][32];
    __shared__ int   mcol_s[128];

    const int t  = threadIdx.x;
    const int w  = t >> 6;
    const int l  = t & 63;
    const int lq = l & 15;
    const int hq = l >> 4;

    // XCD-aware bijective swizzle (512 blocks, 8 XCDs, 64 each = 4 panels)
    const int lin = blockIdx.x;
    const int swz = (lin & 7) * 64 + (lin >> 3);
    const int qb = swz & 15;            // 0..15
    const int h  = (swz >> 4) & 15;     // 0..15
    const int b  = swz >> 8;            // 0..1
    const int i0 = qb * 128 + w * 32;   // wave's first q row

    // staging decompositions (it-invariant parts)
    const int sj = t >> 3;              // K stage: row = it*32 + sj
    const int sd = (t & 7) * 8;         //          col = sd
    const int vd = t >> 4;              // V stage: row = it*16 + vd
    const int vj = (t & 15) * 8;        //          col = vj

    // ---- Q fragments, 2 row-groups: A[m=lq][k=kb*32+hq*8+e] ----
    short8v qa[2][2];
#pragma unroll
    for (int g = 0; g < 2; ++g) {
        const short* qrow = q + ((size_t)(b * N_ + i0 + g * 16 + lq)) * C_ + h * D_;
        qa[g][0] = *(const short8v*)&qrow[hq * 8];
        qa[g][1] = *(const short8v*)&qrow[32 + hq * 8];
    }

    int mr[2][4];
#pragma unroll
    for (int g = 0; g < 2; ++g)
#pragma unroll
        for (int r = 0; r < 4; ++r) mr[g][r] = mask[b * N_ + i0 + g * 16 + hq * 4 + r];

    const short* kbase = kv + (size_t)b * N_ * 2 * C_ + h * D_;
    const short* vtb   = vtg + ((size_t)(b * H_ + h)) * D_ * N_;

    // ---------------- pass 1: row sums only ----------------
    float lsum[2][4];
#pragma unroll
    for (int g = 0; g < 2; ++g)
#pragma unroll
        for (int r = 0; r < 4; ++r) lsum[g][r] = 0.f;

    short8v kr[4];
    int mpre = 0;
#pragma unroll
    for (int it = 0; it < 4; ++it)
        kr[it] = *(const short8v*)&kbase[(size_t)(it * 32 + sj) * (2 * C_) + sd];
    if (t < 128) mpre = mask[b * N_ + t];

    for (int tile = 0; tile < 16; ++tile) {
        __syncthreads();
#pragma unroll
        for (int it = 0; it < 4; ++it)
            *(short8v*)&Ks[it * 32 + sj][sd] = kr[it];
        if (t < 128) mcol_s[t] = mpre;
        __syncthreads();

        if (tile < 15) {
            const int jn = (tile + 1) * 128;
#pragma unroll
            for (int it = 0; it < 4; ++it)
                kr[it] = *(const short8v*)&kbase[(size_t)(jn + it * 32 + sj) * (2 * C_) + sd];
            if (t < 128) mpre = mask[b * N_ + jn + t];
        }

#pragma unroll
        for (int cb = 0; cb < 8; ++cb) {
            const short8v b0 = *(short8v*)&Ks[cb * 16 + lq][hq * 8];
            const short8v b1 = *(short8v*)&Ks[cb * 16 + lq][32 + hq * 8];
            const int mc = mcol_s[cb * 16 + lq];
#pragma unroll
            for (int g = 0; g < 2; ++g) {
                f32x4 acc = {0.f, 0.f, 0.f, 0.f};
                acc = __builtin_amdgcn_mfma_f32_16x16x32_bf16(qa[g][0], b0, acc, 0, 0, 0);
                acc = __builtin_amdgcn_mfma_f32_16x16x32_bf16(qa[g][1], b1, acc, 0, 0, 0);
#pragma unroll
                for (int r = 0; r < 4; ++r)
                    lsum[g][r] += mr[g][r] ? 1.0f : (mc ? 0.0f : __expf(acc[r] * 0.125f));
            }
        }
    }
    float inv[2][4];
#pragma unroll
    for (int g = 0; g < 2; ++g)
#pragma unroll
        for (int r = 0; r < 4; ++r) {
            float s = lsum[g][r];
#pragma unroll
            for (int off = 1; off < 16; off <<= 1) s += __shfl_xor(s, off, 64);
            inv[g][r] = 1.0f / s;
        }
    if (lq == 0)
#pragma unroll
        for (int g = 0; g < 2; ++g)
#pragma unroll
            for (int r = 0; r < 4; ++r) linv_s[w][g * 16 + hq * 4 + r] = inv[g][r];

    float* wbase[2];
#pragma unroll
    for (int g = 0; g < 2; ++g)
        wbase[g] = out_w + ((size_t)((b * H_ + h) * N_ + i0 + g * 16 + hq * 4)) * N_;

    f32x4 oacc[4][2];
#pragma unroll
    for (int db = 0; db < 4; ++db)
#pragma unroll
        for (int g = 0; g < 2; ++g) oacc[db][g] = (f32x4){0.f, 0.f, 0.f, 0.f};

    // ---------------- pass 2 ----------------
    short8v vr[4];
#pragma unroll
    for (int it = 0; it < 4; ++it) {
        kr[it] = *(const short8v*)&kbase[(size_t)(it * 32 + sj) * (2 * C_) + sd];
        vr[it] = *(const short8v*)&vtb[(size_t)(it * 16 + vd) * N_ + vj];
    }
    if (t < 128) mpre = mask[b * N_ + t];

    for (int tile = 0; tile < 16; ++tile) {
        const int jt = tile * 128;
        __syncthreads();
#pragma unroll
        for (int it = 0; it < 4; ++it) {
            *(short8v*)&Ks[it * 32 + sj][sd] = kr[it];
            *(short8v*)&Vt[it * 16 + vd][vj] = vr[it];
        }
        if (t < 128) mcol_s[t] = mpre;
        __syncthreads();

        if (tile < 15) {
            const int jn = jt + 128;
#pragma unroll
            for (int it = 0; it < 4; ++it) {
                kr[it] = *(const short8v*)&kbase[(size_t)(jn + it * 32 + sj) * (2 * C_) + sd];
                vr[it] = *(const short8v*)&vtb[(size_t)(it * 16 + vd) * N_ + jn + vj];
            }
            if (t < 128) mpre = mask[b * N_ + jn + t];
        }

#pragma unroll
        for (int cb = 0; cb < 8; ++cb) {
            const short8v b0 = *(short8v*)&Ks[cb * 16 + lq][hq * 8];
            const short8v b1 = *(short8v*)&Ks[cb * 16 + lq][32 + hq * 8];
            const int mc   = mcol_s[cb * 16 + lq];
            const int jcol = cb * 16 + lq;
#pragma unroll
            for (int g = 0; g < 2; ++g) {
                f32x4 acc = {0.f, 0.f, 0.f, 0.f};
                acc = __builtin_amdgcn_mfma_f32_16x16x32_bf16(qa[g][0], b0, acc, 0, 0, 0);
                acc = __builtin_amdgcn_mfma_f32_16x16x32_bf16(qa[g][1], b1, acc, 0, 0, 0);
#pragma unroll
                for (int r = 0; r < 4; ++r) {
                    const float ev = mr[g][r] ? 1.0f : (mc ? 0.0f : __expf(acc[r] * 0.125f));
                    wbase[g][(size_t)r * N_ + jt + jcol] = ev * inv[g][r];   // normalized weight
                    Ps[w][g * 16 + hq * 4 + r][jcol] = f2bf(ev);
                }
            }
        }
        __syncthreads();   // REQUIRED: Ps writes -> cross-lane PV reads

        // att^T += V^T @ P  (pb hoisted: db-invariant)
        short8v pb[2][4];
#pragma unroll
        for (int kb = 0; kb < 4; ++kb) {
            pb[0][kb] = *(short8v*)&Ps[w][lq][kb * 32 + hq * 8];
            pb[1][kb] = *(short8v*)&Ps[w][16 + lq][kb * 32 + hq * 8];
        }
#pragma unroll
        for (int db = 0; db < 4; ++db)
#pragma unroll
            for (int kb = 0; kb < 4; ++kb) {
                const short8v va = *(short8v*)&Vt[db * 16 + lq][kb * 32 + hq * 8];
                oacc[db][0] = __builtin_amdgcn_mfma_f32_16x16x32_bf16(va, pb[0][kb], oacc[db][0], 0, 0, 0);
                oacc[db][1] = __builtin_amdgcn_mfma_f32_16x16x32_bf16(va, pb[1][kb], oacc[db][1], 0, 0, 0);
            }
    }

    // ---- att: scale accumulators, scalar stores (row=g*16+lq, d=db*16+hq*4+r) ----
#pragma unroll
    for (int g = 0; g < 2; ++g) {
        const float invi = linv_s[w][g * 16 + lq];
        const size_t abase = ((size_t)(b * N_ + i0 + g * 16 + lq)) * C_ + h * D_;
#pragma unroll
        for (int db = 0; db < 4; ++db)
#pragma unroll
            for (int r = 0; r < 4; ++r)
                out_att[abase + db * 16 + hq * 4 + r] = oacc[db][g][r] * invi;
    }
}

// ---------------------------------------------------------------------------
extern "C" void kernel_launch(void* const* d_in, const int* in_sizes, int n_in,
                              void* d_out, int out_size, void* d_ws, size_t ws_size,
                              hipStream_t stream) {
    const float* hs   = (const float*)d_in[0];
    const float* ehs  = (const float*)d_in[1];
    const int*   mask = (const int*)d_in[2];
    const float* W_q  = (const float*)d_in[3];
    const float* W_c  = (const float*)d_in[4];

    float* out_att = (float*)d_out;
    float* out_w   = (float*)d_out + (size_t)B_ * N_ * C_;

    short* qbf  = (short*)d_ws;                          // B*N*C
    short* kvbf = qbf + (size_t)B_ * N_ * C_;            // B*N*2C
    short* vt   = kvbf + (size_t)B_ * N_ * 2 * C_;       // B*H*D*N

    gemm_x3<<<dim3(C_ / 64, (B_ * N_) / 128), 256, 0, stream>>>(
        hs, W_q, qbf, C_, C_);
    gemm_x3<<<dim3((2 * C_) / 64, (B_ * N_) / 128), 256, 0, stream>>>(
        ehs, W_c, kvbf, C_, 2 * C_);
    v_transpose<<<dim3(N_ / 128, H_, B_), 256, 0, stream>>>(kvbf, vt);

    attn_mfma<<<dim3(512), 256, 0, stream>>>(
        qbf, kvbf, vt, mask, out_att, out_w);
}